// Round 5
// baseline (952.203 us; speedup 1.0000x reference)
//
#include <hip/hip_runtime.h>
#include <hip/hip_bf16.h>
#include <math.h>

#define NN 100000
#define NNP 100096          // padded to 782*128
#define NE 300000
#define HID 128
#define EMB 64
#define NG 4096
#define DEG_CAP 32
#define XS 512              // X row stride in elements

typedef __bf16 bf16x8 __attribute__((ext_vector_type(8)));
typedef float  f32x16 __attribute__((ext_vector_type(16)));
typedef short  short8 __attribute__((ext_vector_type(8)));

typedef const __attribute__((address_space(1))) unsigned int* gas_u32;
typedef __attribute__((address_space(3))) unsigned int* las_u32;

__device__ __forceinline__ void gload16(const void* g, void* l) {
    // async global->LDS DMA, 16B/lane; LDS dest = wave-uniform base + lane*16
    __builtin_amdgcn_global_load_lds((gas_u32)g, (las_u32)l, 16, 0, 0);
}

__device__ __forceinline__ float bf2f(unsigned short u) {
    unsigned int x = ((unsigned int)u) << 16;
    return __builtin_bit_cast(float, x);
}
__device__ __forceinline__ unsigned short f2bf(float f) {
    unsigned int x = __builtin_bit_cast(unsigned int, f);
    unsigned int r = x + 0x7fff + ((x >> 16) & 1);
    return (unsigned short)(r >> 16);
}
__device__ __forceinline__ float sigm(float x) { return 1.f / (1.f + __expf(-x)); }

// ---------------------------------------------------------------------------
// h init: node_features f32 -> X[:,384:512] bf16
// ---------------------------------------------------------------------------
__global__ __launch_bounds__(256) void k_init(const float* __restrict__ nf,
                                              unsigned short* __restrict__ X) {
    int id = blockIdx.x * 256 + threadIdx.x;   // NN*HID
    int n = id >> 7, c = id & 127;
    X[(long)n * XS + 384 + c] = f2bf(nf[id]);
}

// ---------------------------------------------------------------------------
// CSR build (deg true counts; csr capped at DEG_CAP)
// ---------------------------------------------------------------------------
__global__ __launch_bounds__(256) void k_build_csr(const int* __restrict__ ei,
                                                   int* __restrict__ deg,
                                                   int* __restrict__ csr) {
    int id = blockIdx.x * 256 + threadIdx.x;
    if (id >= 3 * NE) return;
    int t = id / NE;
    int i = id - t * NE;
    int src = ei[(t * 2 + 0) * NE + i];
    int dst = ei[(t * 2 + 1) * NE + i];
    int p = atomicAdd(&deg[t * NN + dst], 1);
    if (p < DEG_CAP) csr[((long)t * NN + dst) * DEG_CAP + p] = src;
}

__global__ __launch_bounds__(256) void k_pack_deg(const int* __restrict__ deg,
                                                  int4* __restrict__ degp) {
    int n = blockIdx.x * 256 + threadIdx.x;
    if (n >= NNP) return;
    int4 v; v.x = 0; v.y = 0; v.z = 0; v.w = 0;
    if (n < NN) { v.x = deg[n]; v.y = deg[NN + n]; v.z = deg[2 * NN + n]; }
    degp[n] = v;
}

// ---------------------------------------------------------------------------
// Wnk[n][k] bf16, n = sec*128+c, K layout: k<384 -> A_cat (Wm @ Wih_sec^T),
// k>=384 -> h (Whh_sec). sec order: 0=r, 1=z, 2=In(i-only), 3=Hn(h-only).
// ---------------------------------------------------------------------------
__global__ __launch_bounds__(512) void k_build_w(const float* __restrict__ Wmsg,
                                                 const float* __restrict__ Wih,
                                                 const float* __restrict__ Whh,
                                                 unsigned short* __restrict__ Wnk) {
    int n = blockIdx.x;        // 0..511
    int k = threadIdx.x;       // 0..511
    int sec = n >> 7, c = n & 127;
    float v = 0.f;
    if (k < 384) {
        if (sec < 3) {
            int t = k >> 7, kk = k & 127;
            const float* wm = Wmsg + ((long)t * HID + kk) * HID;       // W_msg[t][kk][:]
            const float* wi = Wih + (long)(sec * HID + c) * HID;       // W_ih[sec*128+c][:]
            float s = 0.f;
            for (int j = 0; j < HID; j++) s += wm[j] * wi[j];
            v = s;
        }
    } else {
        int kk = k - 384;
        if (sec == 0)      v = Whh[(long)c * HID + kk];
        else if (sec == 1) v = Whh[(long)(HID + c) * HID + kk];
        else if (sec == 3) v = Whh[(long)(2 * HID + c) * HID + kk];
    }
    Wnk[(long)n * 512 + k] = f2bf(v);
}

__global__ __launch_bounds__(512) void k_build_bias(const float* __restrict__ bih,
                                                    const float* __restrict__ bhh,
                                                    const float* __restrict__ bmsg,
                                                    const float* __restrict__ Wih,
                                                    float* __restrict__ bbig,
                                                    float* __restrict__ Bdeg) {
    int n = threadIdx.x;       // 0..511
    int sec = n >> 7, c = n & 127;
    float b;
    if (sec == 0)      b = bih[c] + bhh[c];
    else if (sec == 1) b = bih[HID + c] + bhh[HID + c];
    else if (sec == 2) b = bih[2 * HID + c];
    else               b = bhh[2 * HID + c];
    bbig[n] = b;
    for (int t = 0; t < 3; t++) {
        float s = 0.f;
        if (sec < 3) {
            const float* wi = Wih + (long)(sec * HID + c) * HID;
            const float* bm = bmsg + t * HID;
            for (int j = 0; j < HID; j++) s += bm[j] * wi[j];
        }
        Bdeg[t * 512 + n] = s;
    }
}

// ---------------------------------------------------------------------------
// Aggregate, MLP-optimized: one WAVE per node. Lane = (g = l>>4 neighbor
// group) x (c16 = l&15 16B chunk). Each short8 load covers 4 neighbors in
// parallel; csr index rows hoisted up front; cross-group reduce via shfl_xor.
// ---------------------------------------------------------------------------
__global__ __launch_bounds__(256) void k_agg(unsigned short* __restrict__ X,
                                             const int* __restrict__ deg,
                                             const int* __restrict__ csr) {
    const int lane = threadIdx.x & 63;
    const long n = (long)blockIdx.x * 4 + (threadIdx.x >> 6);
    const int g = lane >> 4;
    const int c16 = lane & 15;
    const int l31 = lane & 31;

    int d[3], il[3];
#pragma unroll
    for (int t = 0; t < 3; t++) {
        int dt = deg[t * NN + n];
        d[t] = dt > DEG_CAP ? DEG_CAP : dt;
        il[t] = csr[((long)t * NN + n) * DEG_CAP + l31];
    }
#pragma unroll
    for (int t = 0; t < 3; t++) {
        float acc[8] = {0.f, 0.f, 0.f, 0.f, 0.f, 0.f, 0.f, 0.f};
        int rounds = (d[t] + 3) >> 2;
        for (int r = 0; r < rounds; r++) {
            int j = r * 4 + g;
            int idx = __shfl(il[t], j & 31);
            if (j < d[t]) {
                short8 v = *(const short8*)(X + (long)idx * XS + 384 + c16 * 8);
#pragma unroll
                for (int q = 0; q < 8; q++) acc[q] += bf2f((unsigned short)v[q]);
            }
        }
#pragma unroll
        for (int q = 0; q < 8; q++) {
            acc[q] += __shfl_xor(acc[q], 16);
            acc[q] += __shfl_xor(acc[q], 32);
        }
        if (g == 0) {
            short8 o;
#pragma unroll
            for (int q = 0; q < 8; q++) o[q] = (short)f2bf(acc[q]);
            *(short8*)(X + n * XS + t * HID + c16 * 8) = o;
        }
    }
}

// ---------------------------------------------------------------------------
// Fused GRU step: [A_cat|h] (K=512) x Wnk (N=512) MFMA GEMM + gates.
// BM=128, BN=512, BK=32, 8 waves, wave tile 64x128 (2x4 of 32x32).
// Staging: global_load_lds DMA (16B) into double-buffered LDS; linear LDS
// dest + pre-swizzled global source + swizzled ds_read (unit ^= (row>>1)&3,
// bijective in row bits 0..2 -> conflict-free b128). ONE barrier per K-step:
// barrier drains vmcnt (buf[cur] ready), issue DMA for buf[cur^1], compute.
// Epilogue: 8 x 16-row chunks through reused LDS (buf0 region).
// ---------------------------------------------------------------------------
__global__ __launch_bounds__(512, 2) void k_gru_mfma(
        const unsigned short* __restrict__ X, unsigned short* __restrict__ Xw,
        const unsigned short* __restrict__ Wnk,
        const float* __restrict__ bbig, const float* __restrict__ Bdeg,
        const int4* __restrict__ degp) {
    __shared__ char lds[81920];     // 2 x (A 8KB + B 32KB)

    const int tid = threadIdx.x;
    const int lane = tid & 63;
    const int wv = tid >> 6;
    const int wr = wv >> 2;         // 0..1
    const int wc = wv & 3;          // 0..3
    const int r31 = lane & 31;
    const int kg = lane >> 5;       // 0..1
    const int swr = (r31 >> 1) & 3; // read-side swizzle key
    const long row0 = (long)blockIdx.x * 128;

    f32x16 acc[2][4];
#pragma unroll
    for (int i = 0; i < 2; i++)
#pragma unroll
        for (int j = 0; j < 4; j++) acc[i][j] = (f32x16)(0.0f);

    // staging: thread covers (srow = tid>>2, unit su = tid&3); source swizzled
    const int srow = tid >> 2;
    const int su = tid & 3;
    const int swu = (su ^ ((srow >> 1) & 3)) * 16;
    const char* pA = (const char*)X + (row0 + srow) * 1024 + swu;
    const char* pB = (const char*)Wnk + (long)srow * 1024 + swu;
    // wave-uniform LDS bases (lane*16 added by HW => content at tid*16, as before)
    const int wvb = wv * 1024;

    // prologue: stage buf0 for it=0
    {
        char* Ad = &lds[wvb];
        char* Bd = &lds[8192 + wvb];
        gload16(pA, Ad);
        gload16(pB, Bd);
        gload16(pB + 131072, Bd + 8192);
        gload16(pB + 262144, Bd + 16384);
        gload16(pB + 393216, Bd + 24576);
    }

    int cur = 0;
    for (int it = 0; it < 16; it++) {
        __syncthreads();            // drains vmcnt(0): buf[cur] is ready
        if (it < 15) {              // fire-and-forget DMA into buf[cur^1]
            long ko = (long)(it + 1) * 64;
            char* Ad = &lds[(cur ^ 1) * 40960 + wvb];
            char* Bd = &lds[(cur ^ 1) * 40960 + 8192 + wvb];
            gload16(pA + ko, Ad);
            gload16(pB + ko, Bd);
            gload16(pB + 131072 + ko, Bd + 8192);
            gload16(pB + 262144 + ko, Bd + 16384);
            gload16(pB + 393216 + ko, Bd + 24576);
        }
        const char* Al = &lds[cur * 40960];
        const char* Bl = &lds[cur * 40960 + 8192];

        short8 af[2][2], bfr[4][2];
#pragma unroll
        for (int rt = 0; rt < 2; rt++)
#pragma unroll
            for (int kb = 0; kb < 2; kb++)
                af[rt][kb] = *(const short8*)(Al + (wr * 64 + rt * 32 + r31) * 64 +
                                              (((2 * kb + kg) ^ swr) * 16));
#pragma unroll
        for (int ct = 0; ct < 4; ct++)
#pragma unroll
            for (int kb = 0; kb < 2; kb++)
                bfr[ct][kb] = *(const short8*)(Bl + (wc * 128 + ct * 32 + r31) * 64 +
                                               (((2 * kb + kg) ^ swr) * 16));
#pragma unroll
        for (int kb = 0; kb < 2; kb++)
#pragma unroll
            for (int rt = 0; rt < 2; rt++)
#pragma unroll
                for (int ct = 0; ct < 4; ct++)
                    acc[rt][ct] = __builtin_amdgcn_mfma_f32_32x32x16_bf16(
                        __builtin_bit_cast(bf16x8, af[rt][kb]),
                        __builtin_bit_cast(bf16x8, bfr[ct][kb]),
                        acc[rt][ct], 0, 0, 0);
        cur ^= 1;
    }

    // ---- epilogue: 8 chunks of 16 rows through LDS exchange (buf0 region) ----
    float* EX = (float*)lds;        // [16][512] f32 = 32 KB
#pragma unroll
    for (int ch = 0; ch < 8; ch++) {
        __syncthreads();
        if (wr == (ch >> 2)) {
            const int rt = (ch >> 1) & 1;
            const int half = ch & 1;
#pragma unroll
            for (int ct = 0; ct < 4; ct++) {
                int n = wc * 128 + ct * 32 + r31;
#pragma unroll
                for (int q = 0; q < 8; q++) {
                    int row16 = (q & 3) + 8 * ((q >> 2) & 1) + 4 * kg;
                    EX[row16 * 512 + n] = acc[rt][ct][half * 8 + q];
                }
            }
        }
        __syncthreads();
        {
            int row16 = tid >> 5;
            int c0 = (tid & 31) << 2;
            long grow = row0 + ch * 16 + row16;
            int4 dg = degp[grow];
            float dgx = (float)dg.x, dgy = (float)dg.y, dgz = (float)dg.z;
            const float* ex = EX + row16 * 512;
            float4 vr = *(const float4*)(ex + c0);
            float4 vz = *(const float4*)(ex + 128 + c0);
            float4 vn = *(const float4*)(ex + 256 + c0);
            float4 vh = *(const float4*)(ex + 384 + c0);
            float4 br = *(const float4*)(bbig + c0);
            float4 bz = *(const float4*)(bbig + 128 + c0);
            float4 bn = *(const float4*)(bbig + 256 + c0);
            float4 bh = *(const float4*)(bbig + 384 + c0);
            float4 d00 = *(const float4*)(Bdeg + c0);
            float4 d01 = *(const float4*)(Bdeg + 128 + c0);
            float4 d02 = *(const float4*)(Bdeg + 256 + c0);
            float4 d10 = *(const float4*)(Bdeg + 512 + c0);
            float4 d11 = *(const float4*)(Bdeg + 512 + 128 + c0);
            float4 d12 = *(const float4*)(Bdeg + 512 + 256 + c0);
            float4 d20 = *(const float4*)(Bdeg + 1024 + c0);
            float4 d21 = *(const float4*)(Bdeg + 1024 + 128 + c0);
            float4 d22 = *(const float4*)(Bdeg + 1024 + 256 + c0);
            ushort4 ho = *(const ushort4*)(X + grow * XS + 384 + c0);

            float aR[4] = {vr.x, vr.y, vr.z, vr.w};
            float aZ[4] = {vz.x, vz.y, vz.z, vz.w};
            float aN[4] = {vn.x, vn.y, vn.z, vn.w};
            float aH[4] = {vh.x, vh.y, vh.z, vh.w};
            float bR[4] = {br.x, br.y, br.z, br.w};
            float bZ[4] = {bz.x, bz.y, bz.z, bz.w};
            float bN[4] = {bn.x, bn.y, bn.z, bn.w};
            float bH[4] = {bh.x, bh.y, bh.z, bh.w};
            float e00[4] = {d00.x, d00.y, d00.z, d00.w};
            float e01[4] = {d01.x, d01.y, d01.z, d01.w};
            float e02[4] = {d02.x, d02.y, d02.z, d02.w};
            float e10[4] = {d10.x, d10.y, d10.z, d10.w};
            float e11[4] = {d11.x, d11.y, d11.z, d11.w};
            float e12[4] = {d12.x, d12.y, d12.z, d12.w};
            float e20[4] = {d20.x, d20.y, d20.z, d20.w};
            float e21[4] = {d21.x, d21.y, d21.z, d21.w};
            float e22[4] = {d22.x, d22.y, d22.z, d22.w};
            unsigned short hold[4] = {ho.x, ho.y, ho.z, ho.w};

            ushort4 outp;
            unsigned short* op = (unsigned short*)&outp;
#pragma unroll
            for (int cc = 0; cc < 4; cc++) {
                float Sr = aR[cc] + bR[cc] + dgx * e00[cc] + dgy * e10[cc] + dgz * e20[cc];
                float Sz = aZ[cc] + bZ[cc] + dgx * e01[cc] + dgy * e11[cc] + dgz * e21[cc];
                float In = aN[cc] + bN[cc] + dgx * e02[cc] + dgy * e12[cc] + dgz * e22[cc];
                float Hn = aH[cc] + bH[cc];
                float rr = sigm(Sr);
                float zz = sigm(Sz);
                float tt = In + rr * Hn;
                float e2 = __expf(2.f * tt);
                float nn = 1.f - 2.f / (e2 + 1.f);
                float hv = (1.f - zz) * nn + zz * bf2f(hold[cc]);
                op[cc] = f2bf(hv);
            }
            *(ushort4*)(Xw + grow * XS + 384 + c0) = outp;
        }
    }
}

// ---------------------------------------------------------------------------
// Readout: out[g] += sigmoid(h@Wg.T+bg) * (h@Wp.T+bp). h from X bf16.
// 32 rows/block, fp32 vector GEMM (tiny FLOPs), block-local rows -> atomics.
// ---------------------------------------------------------------------------
__global__ __launch_bounds__(256) void k_readout(const unsigned short* __restrict__ X,
                                                 const int* __restrict__ n2g,
                                                 const float* __restrict__ Wp,
                                                 const float* __restrict__ bp,
                                                 const float* __restrict__ Wg,
                                                 const float* __restrict__ bg,
                                                 float* __restrict__ out) {
    __shared__ float hs[32][132];
    __shared__ float Ws[64][129];
    int tid = threadIdx.x;
    long row0 = (long)blockIdx.x * 32;
    int rg = tid >> 5, cg = tid & 31;
    float acc[4][4];
#pragma unroll
    for (int r = 0; r < 4; r++)
#pragma unroll
        for (int c = 0; c < 4; c++) acc[r][c] = 0.f;

#pragma unroll
    for (int p = 0; p < 2; p++) {
        int e = p * 256 + tid;
        int r = e >> 4, c8 = e & 15;
        short8 v = *(const short8*)(X + (row0 + r) * XS + 384 + c8 * 8);
#pragma unroll
        for (int j = 0; j < 8; j++) hs[r][c8 * 8 + j] = bf2f((unsigned short)v[j]);
    }
    for (int kc = 0; kc < 128; kc += 64) {
        __syncthreads();
#pragma unroll
        for (int p = 0; p < 8; p++) {
            int idx = p * 256 + tid;
            int j = idx >> 4, q = idx & 15;
            const float* Wsrc = (j < 64) ? Wp : Wg;
            float4 w = *(const float4*)&Wsrc[(j & 63) * HID + kc + q * 4];
            Ws[q * 4 + 0][j] = w.x;
            Ws[q * 4 + 1][j] = w.y;
            Ws[q * 4 + 2][j] = w.z;
            Ws[q * 4 + 3][j] = w.w;
        }
        __syncthreads();
#pragma unroll 8
        for (int k = 0; k < 64; k++) {
            float a[4], w[4];
#pragma unroll
            for (int r = 0; r < 4; r++) a[r] = hs[rg * 4 + r][kc + k];
#pragma unroll
            for (int c = 0; c < 4; c++) w[c] = Ws[k][cg + 32 * c];
#pragma unroll
            for (int r = 0; r < 4; r++)
#pragma unroll
                for (int c = 0; c < 4; c++) acc[r][c] += a[r] * w[c];
        }
    }
#pragma unroll
    for (int r = 0; r < 4; r++) {
        long row = row0 + rg * 4 + r;
        if (row < NN) {
            int g = n2g[row];
            float pv0 = acc[r][0] + bp[cg];
            float pv1 = acc[r][1] + bp[cg + 32];
            float gv0 = acc[r][2] + bg[cg];
            float gv1 = acc[r][3] + bg[cg + 32];
            atomicAdd(&out[g * EMB + cg],      pv0 * sigm(gv0));
            atomicAdd(&out[g * EMB + cg + 32], pv1 * sigm(gv1));
        }
    }
}

// ---------------------------------------------------------------------------
extern "C" void kernel_launch(void* const* d_in, const int* in_sizes, int n_in,
                              void* d_out, int out_size, void* d_ws, size_t ws_size,
                              hipStream_t stream) {
    const float* node_features = (const float*)d_in[0];
    const int*   edge_index    = (const int*)d_in[1];
    const int*   n2g           = (const int*)d_in[2];
    const float* W_msg         = (const float*)d_in[3];
    const float* b_msg         = (const float*)d_in[4];
    const float* W_ih          = (const float*)d_in[5];
    const float* W_hh          = (const float*)d_in[6];
    const float* b_ih          = (const float*)d_in[7];
    const float* b_hh          = (const float*)d_in[8];
    const float* W_proj        = (const float*)d_in[9];
    const float* b_proj        = (const float*)d_in[10];
    const float* W_gate        = (const float*)d_in[11];
    const float* b_gate        = (const float*)d_in[12];

    char* ws = (char*)d_ws;
    unsigned short* X    = (unsigned short*)(ws);                 // 102,498,304 B
    unsigned short* Wnk  = (unsigned short*)(ws + 102498304);     //    524,288 B
    float*          bbig = (float*)         (ws + 103022592);     //      2,048 B
    float*          Bdeg = (float*)         (ws + 103024640);     //      6,144 B
    int4*           degp = (int4*)          (ws + 103030784);     //  1,601,536 B
    int*            deg  = (int*)           (ws + 104632320);     //  1,200,000 B
    int*            csr  = (int*)           (ws + 105832320);     // 38,400,000 B -> 144,232,320

    float* out = (float*)d_out;

    hipMemsetAsync(out, 0, (size_t)NG * EMB * sizeof(float), stream);
    hipMemsetAsync(deg, 0, (size_t)3 * NN * sizeof(int), stream);

    k_init<<<dim3((NN * HID) / 256), dim3(256), 0, stream>>>(node_features, X);
    k_build_csr<<<dim3((3 * NE + 255) / 256), dim3(256), 0, stream>>>(edge_index, deg, csr);
    k_pack_deg<<<dim3(NNP / 256), dim3(256), 0, stream>>>(deg, degp);
    k_build_w<<<dim3(512), dim3(512), 0, stream>>>(W_msg, W_ih, W_hh, Wnk);
    k_build_bias<<<dim3(1), dim3(512), 0, stream>>>(b_ih, b_hh, b_msg, W_ih, bbig, Bdeg);

    for (int step = 0; step < 4; step++) {
        k_agg<<<dim3(NN / 4), dim3(256), 0, stream>>>(X, deg, csr);
        k_gru_mfma<<<dim3(NNP / 128), dim3(512), 0, stream>>>(X, X, Wnk, bbig, Bdeg, degp);
    }
    k_readout<<<dim3(NN / 32), dim3(256), 0, stream>>>(X, n2g, W_proj, b_proj,
                                                       W_gate, b_gate, out);
}